// Round 14
// baseline (74.174 us; speedup 1.0000x reference)
//
#include <hip/hip_runtime.h>
#include <hip/hip_cooperative_groups.h>
#include <math.h>

namespace cg = cooperative_groups;

#define TILE_SZ 16
#define NEARP 0.8f
#define FARP 1000.0f
#define ATHR (1.0f/255.0f)
#define TTHR 0.0001f

// Record layout (16 floats, 64B), float4-aligned groups:
//  g0 [0:3]   = u, v, conic_a, conic_b
//  g1 [4:7]   = conic_c, alpha, z, color_r
//  g2 [8:11]  = color_g, color_b, pad, pad
//  g3 [12:15] = u, v, rmax2, packed_bounds(u8 t0x,t1x,t0y,t1y)  <- membership

#define LIST_CAP 2048

#define COMPOSITE(P0,P1,P2) do { \
    float du = pxf - P0.x; \
    float dv = pyf - P0.y; \
    float power = -0.5f * (P0.z*du*du + P1.x*dv*dv) - P0.w*du*dv; \
    float e = __expf(power); \
    float ai = fminf(fminf(P1.y * e, P1.y), 0.99f); \
    bool eff = (ai >= ATHR) && (T > TTHR); \
    float w = eff ? T * ai : 0.0f; \
    cr  += w * P1.w; \
    cg2 += w * P2.x; \
    cbl += w * P2.y; \
    dep += w * P1.z; \
    acc += w; \
    cnt_px += eff; \
    T = eff ? T * (1.0f - ai) : T; \
} while (0)

// ONE cooperative kernel: prep+rank -> grid.sync -> scatter -> grid.sync -> raster.
// Grid = 64 blocks x 256 threads (nchunks^2 == tiles == 64 for this problem).
__global__ __launch_bounds__(256) void mega_kernel(
        const float* __restrict__ pc,
        const float* __restrict__ feat,
        const int* __restrict__ invalid_mask,
        const float* __restrict__ K,
        const float* __restrict__ qcam,
        const float* __restrict__ tcam,
        const int* __restrict__ cam_h,
        const int* __restrict__ cam_w,
        const int* __restrict__ sh_band,
        float* __restrict__ recs,
        int* __restrict__ partial,
        float* __restrict__ sorted_recs,
        float* __restrict__ out,
        int N, int nchunks)
{
    cg::grid_group grid = cg::this_grid();

    __shared__ float sk[256];
    __shared__ unsigned short wlist[4][LIST_CAP];  // 16KB (phase 3)
    __shared__ float swave[4][2][64 * 16];         // 32KB (phase 3)

    int tid = threadIdx.x;
    float fx = K[0], cx = K[2], fy = K[4], cy = K[5];
    int H = cam_h[0], W = cam_w[0];

    float qx = qcam[0], qy = qcam[1], qz = qcam[2], qw = qcam[3];
    float qn = sqrtf(qx*qx + qy*qy + qz*qz + qw*qw);
    qx /= qn; qy /= qn; qz /= qn; qw /= qn;
    float R00 = 1.f-2.f*(qy*qy+qz*qz), R01 = 2.f*(qx*qy-qw*qz), R02 = 2.f*(qx*qz+qw*qy);
    float R10 = 2.f*(qx*qy+qw*qz), R11 = 1.f-2.f*(qx*qx+qz*qz), R12 = 2.f*(qy*qz-qw*qx);
    float R20 = 2.f*(qx*qz-qw*qy), R21 = 2.f*(qy*qz+qw*qx), R22 = 1.f-2.f*(qx*qx+qy*qy);
    float C00 = R00, C01 = R10, C02 = R20;
    float C10 = R01, C11 = R11, C12 = R21;
    float C20 = R02, C21 = R12, C22 = R22;
    float tx = tcam[0], ty = tcam[1], tz = tcam[2];
    float tcx = -(C00*tx + C01*ty + C02*tz);
    float tcy = -(C10*tx + C11*ty + C12*tz);
    float tcz = -(C20*tx + C21*ty + C22*tz);

    // ================= Phase 1: prep + 2D rank (R12 verbatim) =================
    if ((int)blockIdx.x < nchunks * nchunks) {
        int b = blockIdx.x;
        int ic = b % nchunks, jc = b / nchunks;
        int i = ic * 256 + tid;

        int jbase = jc * 256;
        {
            int j = jbase + tid;
            if (j < N) {
                float px = pc[j*3+0], py = pc[j*3+1], pz = pc[j*3+2];
                float xc = C00*px + C01*py + C02*pz + tcx;
                float yc = C10*px + C11*py + C12*pz + tcy;
                float zc = C20*px + C21*py + C22*pz + tcz;
                float inv_z = 1.0f / zc;
                float u = fx * xc * inv_z + cx;
                float v = fy * yc * inv_z + cy;
                bool valid = (invalid_mask[j] == 0) && (zc > NEARP) && (zc < FARP)
                          && (u > -4.0f*TILE_SZ) && (u < (float)W + 4.0f*TILE_SZ)
                          && (v > -4.0f*TILE_SZ) && (v < (float)H + 4.0f*TILE_SZ);
                sk[tid] = valid ? zc : INFINITY;
            }
        }
        __syncthreads();

        if (i < N) {
            float px = pc[i*3+0], py = pc[i*3+1], pz = pc[i*3+2];
            float xc = C00*px + C01*py + C02*pz + tcx;
            float yc = C10*px + C11*py + C12*pz + tcy;
            float zc = C20*px + C21*py + C22*pz + tcz;
            float inv_z = 1.0f / zc;
            float u = fx * xc * inv_z + cx;
            float v = fy * yc * inv_z + cy;
            bool valid = (invalid_mask[i] == 0) && (zc > NEARP) && (zc < FARP)
                      && (u > -4.0f*TILE_SZ) && (u < (float)W + 4.0f*TILE_SZ)
                      && (v > -4.0f*TILE_SZ) && (v < (float)H + 4.0f*TILE_SZ);
            float ki = valid ? zc : INFINITY;

            int m = min(256, N - jbase);
            int r = 0;
            int m4 = m & ~3;
#pragma unroll 4
            for (int j = 0; j < m4; j += 4) {
                float4 k4 = *(const float4*)(sk + j);
                r += (k4.x < ki) || (k4.x == ki && (jbase + j    ) < i);
                r += (k4.y < ki) || (k4.y == ki && (jbase + j + 1) < i);
                r += (k4.z < ki) || (k4.z == ki && (jbase + j + 2) < i);
                r += (k4.w < ki) || (k4.w == ki && (jbase + j + 3) < i);
            }
            for (int j = m4; j < m; j++) {
                float kj = sk[j];
                r += (kj < ki) || (kj == ki && (jbase + j) < i);
            }
            partial[jc * N + i] = r;

            if (jc == 0) {
                float fv[56];
                const float4* f4 = (const float4*)(feat + (size_t)i * 56);
#pragma unroll
                for (int k = 0; k < 14; k++) {
                    float4 t = f4[k];
                    fv[4*k+0] = t.x; fv[4*k+1] = t.y; fv[4*k+2] = t.z; fv[4*k+3] = t.w;
                }
                float q0 = fv[0], q1 = fv[1], q2 = fv[2], q3 = fv[3];
                float pn = sqrtf(q0*q0 + q1*q1 + q2*q2 + q3*q3);
                q0 /= pn; q1 /= pn; q2 /= pn; q3 /= pn;
                float P00 = 1.f-2.f*(q1*q1+q2*q2), P01 = 2.f*(q0*q1-q3*q2), P02 = 2.f*(q0*q2+q3*q1);
                float P10 = 2.f*(q0*q1+q3*q2), P11 = 1.f-2.f*(q0*q0+q2*q2), P12 = 2.f*(q1*q2-q3*q0);
                float P20 = 2.f*(q0*q2-q3*q1), P21 = 2.f*(q1*q2+q3*q0), P22 = 1.f-2.f*(q0*q0+q1*q1);
                float s0 = expf(fv[4]), s1 = expf(fv[5]), s2 = expf(fv[6]);
                float M00 = P00*s0, M01 = P01*s1, M02 = P02*s2;
                float M10 = P10*s0, M11 = P11*s1, M12 = P12*s2;
                float M20 = P20*s0, M21 = P21*s1, M22 = P22*s2;
                float S00 = M00*M00 + M01*M01 + M02*M02;
                float S01 = M00*M10 + M01*M11 + M02*M12;
                float S02 = M00*M20 + M01*M21 + M02*M22;
                float S11 = M10*M10 + M11*M11 + M12*M12;
                float S12 = M10*M20 + M11*M21 + M12*M22;
                float S22 = M20*M20 + M21*M21 + M22*M22;
                float T00 = C00*S00 + C01*S01 + C02*S02;
                float T01 = C00*S01 + C01*S11 + C02*S12;
                float T02 = C00*S02 + C01*S12 + C02*S22;
                float T10 = C10*S00 + C11*S01 + C12*S02;
                float T11 = C10*S01 + C11*S11 + C12*S12;
                float T12 = C10*S02 + C11*S12 + C12*S22;
                float T20 = C20*S00 + C21*S01 + C22*S02;
                float T21 = C20*S01 + C21*S11 + C22*S12;
                float T22 = C20*S02 + C21*S12 + C22*S22;
                float G00 = T00*C00 + T01*C01 + T02*C02;
                float G01 = T00*C10 + T01*C11 + T02*C12;
                float G02 = T00*C20 + T01*C21 + T02*C22;
                float G11 = T10*C10 + T11*C11 + T12*C12;
                float G12 = T10*C20 + T11*C21 + T12*C22;
                float G22 = T20*C20 + T21*C21 + T22*C22;
                float j00 = fx * inv_z;
                float j02 = -fx * xc * inv_z * inv_z;
                float j11 = fy * inv_z;
                float j12 = -fy * yc * inv_z * inv_z;
                float a0 = j00*G00 + j02*G02;
                float a1 = j00*G01 + j02*G12;
                float a2 = j00*G02 + j02*G22;
                float b1 = j11*G11 + j12*G12;
                float b2 = j11*G12 + j12*G22;
                float cov00 = a0*j00 + a2*j02;
                float cov01 = a1*j11 + a2*j12;
                float cov11 = b1*j11 + b2*j12;

                float A = cov00 + 0.3f;
                float B = cov01;
                float Cc = cov11 + 0.3f;
                float det = fmaxf(A*Cc - B*B, 1e-9f);
                float conic_a = Cc / det;
                float conic_b = -B / det;
                float conic_c = A / det;
                float mid = 0.5f * (A + Cc);
                float lam = mid + sqrtf(fmaxf(mid*mid - det, 1e-9f));
                float radii = ceilf(3.0f * sqrtf(lam));

                float alpha = 1.0f / (1.0f + expf(-fv[7]));

                float dnx = px - tx, dny = py - ty, dnz = pz - tz;
                float dn = sqrtf(dnx*dnx + dny*dny + dnz*dnz);
                float dx = dnx/dn, dy = dny/dn, dz = dnz/dn;
                float xx = dx*dx, yy = dy*dy, zz = dz*dz;
                float xy = dx*dy, yz = dy*dz, xz = dx*dz;
                float basis[16];
                basis[0] = 0.28209479177387814f;
                basis[1] = -0.4886025119029199f * dy;
                basis[2] = 0.4886025119029199f * dz;
                basis[3] = -0.4886025119029199f * dx;
                basis[4] = 1.0925484305920792f * xy;
                basis[5] = -1.0925484305920792f * yz;
                basis[6] = 0.31539156525252005f * (2.f*zz - xx - yy);
                basis[7] = -1.0925484305920792f * xz;
                basis[8] = 0.5462742152960396f * (xx - yy);
                basis[9] = -0.5900435899266435f * dy * (3.f*xx - yy);
                basis[10] = 2.890611442640554f * xy * dz;
                basis[11] = -0.4570457994644658f * dy * (4.f*zz - xx - yy);
                basis[12] = 0.3731763325901154f * dz * (2.f*zz - 3.f*xx - 3.f*yy);
                basis[13] = -0.4570457994644658f * dx * (4.f*zz - xx - yy);
                basis[14] = 1.445305721320277f * dz * (xx - yy);
                basis[15] = -0.5900435899266435f * dx * (xx - 3.f*yy);
                int band = sh_band[0];
                int kc = (band + 1) * (band + 1);
                float c0 = 0.f, c1 = 0.f, c2 = 0.f;
#pragma unroll
                for (int j = 0; j < 16; j++) {
                    if (j < kc) {
                        c0 += basis[j] * fv[8 + 0*16 + j];
                        c1 += basis[j] * fv[8 + 1*16 + j];
                        c2 += basis[j] * fv[8 + 2*16 + j];
                    }
                }
                c0 = fmaxf(c0 + 0.5f, 0.0f);
                c1 = fmaxf(c1 + 0.5f, 0.0f);
                c2 = fmaxf(c2 + 0.5f, 0.0f);

                float tiles_x = (float)(W / TILE_SZ);
                float tiles_y = (float)(H / TILE_SZ);
                float t0x = fminf(fmaxf(floorf((u - radii) / TILE_SZ), 0.0f), tiles_x - 1.0f);
                float t1x = fminf(fmaxf(floorf((u + radii) / TILE_SZ), 0.0f), tiles_x - 1.0f);
                float t0y = fminf(fmaxf(floorf((v - radii) / TILE_SZ), 0.0f), tiles_y - 1.0f);
                float t1y = fminf(fmaxf(floorf((v + radii) / TILE_SZ), 0.0f), tiles_y - 1.0f);

                unsigned pb;
                float rmax2;
                if (valid) {
                    pb = (unsigned)(int)t0x | ((unsigned)(int)t1x << 8)
                       | ((unsigned)(int)t0y << 16) | ((unsigned)(int)t1y << 24);
                    rmax2 = 2.0f * lam * logf(255.0f * alpha);
                    if (!(rmax2 >= 0.0f)) rmax2 = -1.0f;
                    else rmax2 = rmax2 * 1.0005f + 1e-3f;
                } else {
                    pb = 0x00FF00FFu;
                    rmax2 = -1.0f;
                    alpha = 0.0f;
                }

                float* r2p = recs + (size_t)i * 16;
                r2p[0] = u;  r2p[1] = v;  r2p[2] = conic_a; r2p[3] = conic_b;
                r2p[4] = conic_c; r2p[5] = alpha; r2p[6] = zc; r2p[7] = c0;
                r2p[8] = c1; r2p[9] = c2; r2p[10] = 0.f; r2p[11] = 0.f;
                r2p[12] = u; r2p[13] = v; r2p[14] = rmax2; r2p[15] = __uint_as_float(pb);
            }
        }
    }

    grid.sync();

    // ================= Phase 2: scatter =================
    {
        int i = blockIdx.x * 256 + tid;
        if (i < N) {
            int rank = 0;
            for (int c = 0; c < nchunks; c++) rank += partial[c * N + i];
            const float4* src = (const float4*)(recs + (size_t)i * 16);
            float4* dst = (float4*)(sorted_recs + (size_t)rank * 16);
            dst[0] = src[0]; dst[1] = src[1]; dst[2] = src[2]; dst[3] = src[3];
        }
    }

    grid.sync();

    // ================= Phase 3: raster (R12 verbatim, block = tile) =================
    {
        int tiles_x = W / TILE_SZ;
        int bx = blockIdx.x % tiles_x;
        int by = blockIdx.x / tiles_x;
        int lane = tid & 63;
        int wv = tid >> 6;
        int qpx0 = bx * TILE_SZ + (wv & 1) * 8;
        int qpy0 = by * TILE_SZ + (wv >> 1) * 8;
        int px = qpx0 + (lane & 7);
        int py = qpy0 + (lane >> 3);
        float pxf = (float)px + 0.5f;
        float pyf = (float)py + 0.5f;
        float qx0 = (float)qpx0 + 0.5f, qx1 = (float)qpx0 + 7.5f;
        float qy0 = (float)qpy0 + 0.5f, qy1 = (float)qpy0 + 7.5f;

        float T = 1.0f;
        float cr = 0.f, cg2 = 0.f, cbl = 0.f;
        float dep = 0.f, acc = 0.f;
        int cnt_px = 0;

        unsigned short* wl = wlist[wv];
        bool wave_done = false;

        for (int seg = 0; seg < N && !wave_done; seg += LIST_CAP) {
            int segN = min(LIST_CAP, N - seg);

            int cnt = 0;
            for (int base = 0; base < segN; base += 512) {
                float4 g[8];
#pragma unroll
                for (int r = 0; r < 8; r++) {
                    int local = base + r * 64 + lane;
                    if (local < segN) {
                        g[r] = *(const float4*)(sorted_recs + (size_t)(seg + local) * 16 + 12);
                    } else {
                        g[r].x = 0.f; g[r].y = 0.f; g[r].z = -1.f;
                        g[r].w = __uint_as_float(0x00FF00FFu);
                    }
                }
#pragma unroll
                for (int r = 0; r < 8; r++) {
                    unsigned ub = __float_as_uint(g[r].w);
                    int b0x = (int)(ub & 0xFFu);
                    int b1x = (int)((ub >> 8) & 0xFFu);
                    int b0y = (int)((ub >> 16) & 0xFFu);
                    int b1y = (int)((ub >> 24) & 0xFFu);
                    bool inbox = (bx >= b0x) && (bx <= b1x) && (by >= b0y) && (by <= b1y);
                    float dxc = g[r].x - fminf(fmaxf(g[r].x, qx0), qx1);
                    float dyc = g[r].y - fminf(fmaxf(g[r].y, qy0), qy1);
                    float r2 = dxc*dxc + dyc*dyc;
                    bool pred = inbox && (r2 <= g[r].z);
                    unsigned long long mm = __ballot(pred);
                    if (pred) {
                        int below = __popcll(mm & ((1ull << lane) - 1ull));
                        wl[cnt + below] = (unsigned short)(base + r * 64 + lane);
                    }
                    cnt += __popcll(mm);
                }
            }

            float* st0 = &swave[wv][0][0];
            float* st1 = &swave[wv][1][0];
            int r0 = lane >> 2;
            int part = lane & 3;

            if (cnt > 0) {
                float4 n0, n1, n2, n3;
                if (r0 < cnt)      n0 = ((const float4*)(sorted_recs + (size_t)(seg + (int)wl[r0]) * 16))[part];
                if (16 + r0 < cnt) n1 = ((const float4*)(sorted_recs + (size_t)(seg + (int)wl[16 + r0]) * 16))[part];
                if (32 + r0 < cnt) n2 = ((const float4*)(sorted_recs + (size_t)(seg + (int)wl[32 + r0]) * 16))[part];
                if (48 + r0 < cnt) n3 = ((const float4*)(sorted_recs + (size_t)(seg + (int)wl[48 + r0]) * 16))[part];
                if (r0 < cnt)      *(float4*)(st0 + (lane) * 4)       = n0;
                if (16 + r0 < cnt) *(float4*)(st0 + (64 + lane) * 4)  = n1;
                if (32 + r0 < cnt) *(float4*)(st0 + (128 + lane) * 4) = n2;
                if (48 + r0 < cnt) *(float4*)(st0 + (192 + lane) * 4) = n3;
            }

            bool wdead = false;
            int buf = 0;
            for (int c = 0; c < cnt && !wdead; c += 64) {
                int ecnt = min(64, cnt - c);
                float* cur = buf ? st1 : st0;
                float* oth = buf ? st0 : st1;
                int cn = c + 64;
                int rem = cnt - cn;

                float4 n0, n1, n2, n3;
                if (rem > 0) {
                    if (r0 < rem)      n0 = ((const float4*)(sorted_recs + (size_t)(seg + (int)wl[cn + r0]) * 16))[part];
                    if (16 + r0 < rem) n1 = ((const float4*)(sorted_recs + (size_t)(seg + (int)wl[cn + 16 + r0]) * 16))[part];
                    if (32 + r0 < rem) n2 = ((const float4*)(sorted_recs + (size_t)(seg + (int)wl[cn + 32 + r0]) * 16))[part];
                    if (48 + r0 < rem) n3 = ((const float4*)(sorted_recs + (size_t)(seg + (int)wl[cn + 48 + r0]) * 16))[part];
                }

                for (int j = 0; j < ecnt; j++) {
                    const float* p = cur + j * 16;
                    float4 p0 = *(const float4*)p;
                    float4 p1 = *(const float4*)(p + 4);
                    float4 p2 = *(const float4*)(p + 8);
                    COMPOSITE(p0, p1, p2);
                }
                wdead = __all(T <= TTHR);

                if (rem > 0) {
                    if (r0 < rem)      *(float4*)(oth + (lane) * 4)       = n0;
                    if (16 + r0 < rem) *(float4*)(oth + (64 + lane) * 4)  = n1;
                    if (32 + r0 < rem) *(float4*)(oth + (128 + lane) * 4) = n2;
                    if (48 + r0 < rem) *(float4*)(oth + (192 + lane) * 4) = n3;
                }
                buf ^= 1;
            }
            wave_done = wdead;
        }

        int pix = py * W + px;
        int HW = H * W;
        out[pix*3 + 0] = cr;
        out[pix*3 + 1] = cg2;
        out[pix*3 + 2] = cbl;
        out[HW*3 + pix] = dep / fmaxf(acc, 1e-6f);
        out[HW*4 + pix] = (float)cnt_px;
    }
}

extern "C" void kernel_launch(void* const* d_in, const int* in_sizes, int n_in,
                              void* d_out, int out_size, void* d_ws, size_t ws_size,
                              hipStream_t stream) {
    const float* pc    = (const float*)d_in[0];
    const float* feat  = (const float*)d_in[1];
    const int*   inval = (const int*)d_in[3];
    const float* K     = (const float*)d_in[4];
    const float* qc    = (const float*)d_in[5];
    const float* tc    = (const float*)d_in[6];
    const int*   camH  = (const int*)d_in[7];
    const int*   camW  = (const int*)d_in[8];
    const int*   band  = (const int*)d_in[9];
    float* out = (float*)d_out;

    int N = in_sizes[0] / 3;
    int side = (int)(sqrt((double)(out_size / 5)) + 0.5);
    int H = side, W = side;

    int nchunks = (N + 255) / 256;
    int tiles = (W / TILE_SZ) * (H / TILE_SZ);
    int nblocks = max(nchunks * nchunks, tiles);

    float* recs = (float*)d_ws;
    float* sorted_recs = recs + (size_t)N * 16;
    int*   partial = (int*)(sorted_recs + (size_t)N * 16);

    void* args[] = {
        (void*)&pc, (void*)&feat, (void*)&inval, (void*)&K, (void*)&qc,
        (void*)&tc, (void*)&camH, (void*)&camW, (void*)&band,
        (void*)&recs, (void*)&partial, (void*)&sorted_recs, (void*)&out,
        (void*)&N, (void*)&nchunks
    };
    hipLaunchCooperativeKernel((const void*)mega_kernel,
                               dim3(nblocks), dim3(256), args, 0, stream);
}

// Round 15
// 40.078 us; speedup vs baseline: 1.8507x; 1.8507x over previous
//
#include <hip/hip_runtime.h>
#include <math.h>

#define TILE_SZ 16
#define NEARP 0.8f
#define FARP 1000.0f
#define ATHR (1.0f/255.0f)
#define TTHR 0.0001f

// Record layout (16 floats, 64B), float4-aligned groups:
//  g0 [0:3]   = u, v, conic_a, conic_b
//  g1 [4:7]   = conic_c, alpha, z, color_r
//  g2 [8:11]  = color_g, color_b, pad, pad
//  g3 [12:15] = u, v, rmax2, packed_bounds(u8 t0x,t1x,t0y,t1y)  <- membership

// ONE kernel = preprocess + stable rank + direct scatter.
// ceil(N/32) blocks x 256 threads. Block owns 32 points. Per key-chunk:
// cooperative key recompute into LDS, 8-way sliced scan (R10's proven-fast
// decomposition). Then threads 0..31 full-preprocess their point (R12
// expressions verbatim) and write the record straight to sorted_recs[rank].
#define RANK_CHUNK 2048

__global__ __launch_bounds__(256) void prep_rank_scatter_kernel(
        const float* __restrict__ pc,
        const float* __restrict__ feat,
        const int* __restrict__ invalid_mask,
        const float* __restrict__ K,
        const float* __restrict__ qcam,
        const float* __restrict__ tcam,
        const int* __restrict__ cam_h,
        const int* __restrict__ cam_w,
        const int* __restrict__ sh_band,
        float* __restrict__ sorted_recs,
        int N)
{
    __shared__ float sk[RANK_CHUNK];
    __shared__ int pr[8][33];
    int tid = threadIdx.x;
    int iLocal = tid & 31;
    int slice = tid >> 5;
    int i = blockIdx.x * 32 + iLocal;
    bool live = (i < N);

    float fx = K[0], cx = K[2], fy = K[4], cy = K[5];
    int H = cam_h[0], W = cam_w[0];

    float qx = qcam[0], qy = qcam[1], qz = qcam[2], qw = qcam[3];
    float qn = sqrtf(qx*qx + qy*qy + qz*qz + qw*qw);
    qx /= qn; qy /= qn; qz /= qn; qw /= qn;
    float R00 = 1.f-2.f*(qy*qy+qz*qz), R01 = 2.f*(qx*qy-qw*qz), R02 = 2.f*(qx*qz+qw*qy);
    float R10 = 2.f*(qx*qy+qw*qz), R11 = 1.f-2.f*(qx*qx+qz*qz), R12 = 2.f*(qy*qz-qw*qx);
    float R20 = 2.f*(qx*qz-qw*qy), R21 = 2.f*(qy*qz+qw*qx), R22 = 1.f-2.f*(qx*qx+qy*qy);
    float C00 = R00, C01 = R10, C02 = R20;
    float C10 = R01, C11 = R11, C12 = R21;
    float C20 = R02, C21 = R12, C22 = R22;
    float tx = tcam[0], ty = tcam[1], tz = tcam[2];
    float tcx = -(C00*tx + C01*ty + C02*tz);
    float tcy = -(C10*tx + C11*ty + C12*tz);
    float tcz = -(C20*tx + C21*ty + C22*tz);

    // ---- own key (same expressions as staged keys -> bit-consistent) ----
    float ki = 0.0f;
    if (live) {
        float px = pc[i*3+0], py = pc[i*3+1], pz = pc[i*3+2];
        float xc = C00*px + C01*py + C02*pz + tcx;
        float yc = C10*px + C11*py + C12*pz + tcy;
        float zc = C20*px + C21*py + C22*pz + tcz;
        float inv_z = 1.0f / zc;
        float u = fx * xc * inv_z + cx;
        float v = fy * yc * inv_z + cy;
        bool valid = (invalid_mask[i] == 0) && (zc > NEARP) && (zc < FARP)
                  && (u > -4.0f*TILE_SZ) && (u < (float)W + 4.0f*TILE_SZ)
                  && (v > -4.0f*TILE_SZ) && (v < (float)H + 4.0f*TILE_SZ);
        ki = valid ? zc : INFINITY;
    }

    // ---- chunked cooperative key recompute + 8-way sliced scan ----
    int rank_acc = 0;
    for (int cb = 0; cb < N; cb += RANK_CHUNK) {
        int m = min(RANK_CHUNK, N - cb);
        for (int t = tid; t < m; t += 256) {
            int j = cb + t;
            float px = pc[j*3+0], py = pc[j*3+1], pz = pc[j*3+2];
            float xc = C00*px + C01*py + C02*pz + tcx;
            float yc = C10*px + C11*py + C12*pz + tcy;
            float zc = C20*px + C21*py + C22*pz + tcz;
            float inv_z = 1.0f / zc;
            float u = fx * xc * inv_z + cx;
            float v = fy * yc * inv_z + cy;
            bool valid = (invalid_mask[j] == 0) && (zc > NEARP) && (zc < FARP)
                      && (u > -4.0f*TILE_SZ) && (u < (float)W + 4.0f*TILE_SZ)
                      && (v > -4.0f*TILE_SZ) && (v < (float)H + 4.0f*TILE_SZ);
            sk[t] = valid ? zc : INFINITY;
        }
        __syncthreads();
        if (live) {
            int js = slice * (RANK_CHUNK / 8);
            int je = min(js + (RANK_CHUNK / 8), m);
            int j = js;
            for (; j + 4 <= je; j += 4) {
                float4 k4 = *(const float4*)(sk + j);
                int ja = cb + j;
                rank_acc += (k4.x < ki) || (k4.x == ki && (ja    ) < i);
                rank_acc += (k4.y < ki) || (k4.y == ki && (ja + 1) < i);
                rank_acc += (k4.z < ki) || (k4.z == ki && (ja + 2) < i);
                rank_acc += (k4.w < ki) || (k4.w == ki && (ja + 3) < i);
            }
            for (; j < je; j++) {
                float kj = sk[j];
                rank_acc += (kj < ki) || (kj == ki && (cb + j) < i);
            }
        }
        __syncthreads();
    }
    pr[slice][iLocal] = rank_acc;
    __syncthreads();

    // ---- threads 0..31: full preprocess of own point, direct scatter ----
    if (tid < 32) {
        int ip = blockIdx.x * 32 + tid;
        if (ip < N) {
            int rank = 0;
#pragma unroll
            for (int s = 0; s < 8; s++) rank += pr[s][tid];

            float fv[56];
            const float4* f4 = (const float4*)(feat + (size_t)ip * 56);
#pragma unroll
            for (int k = 0; k < 14; k++) {
                float4 t = f4[k];
                fv[4*k+0] = t.x; fv[4*k+1] = t.y; fv[4*k+2] = t.z; fv[4*k+3] = t.w;
            }
            float px = pc[ip*3+0], py = pc[ip*3+1], pz = pc[ip*3+2];
            float xc = C00*px + C01*py + C02*pz + tcx;
            float yc = C10*px + C11*py + C12*pz + tcy;
            float zc = C20*px + C21*py + C02*0.f + C20*0.f + C21*0.f + tcz
                       - (C20*0.f + C21*0.f) ; // placeholder removed below
            zc = C20*px + C21*py + C22*pz + tcz;
            float inv_z = 1.0f / zc;
            float u = fx * xc * inv_z + cx;
            float v = fy * yc * inv_z + cy;
            bool valid = (invalid_mask[ip] == 0) && (zc > NEARP) && (zc < FARP)
                      && (u > -4.0f*TILE_SZ) && (u < (float)W + 4.0f*TILE_SZ)
                      && (v > -4.0f*TILE_SZ) && (v < (float)H + 4.0f*TILE_SZ);

            float q0 = fv[0], q1 = fv[1], q2 = fv[2], q3 = fv[3];
            float pn = sqrtf(q0*q0 + q1*q1 + q2*q2 + q3*q3);
            q0 /= pn; q1 /= pn; q2 /= pn; q3 /= pn;
            float P00 = 1.f-2.f*(q1*q1+q2*q2), P01 = 2.f*(q0*q1-q3*q2), P02 = 2.f*(q0*q2+q3*q1);
            float P10 = 2.f*(q0*q1+q3*q2), P11 = 1.f-2.f*(q0*q0+q2*q2), P12 = 2.f*(q1*q2-q3*q0);
            float P20 = 2.f*(q0*q2-q3*q1), P21 = 2.f*(q1*q2+q3*q0), P22 = 1.f-2.f*(q0*q0+q1*q1);
            float s0 = expf(fv[4]), s1 = expf(fv[5]), s2 = expf(fv[6]);
            float M00 = P00*s0, M01 = P01*s1, M02 = P02*s2;
            float M10 = P10*s0, M11 = P11*s1, M12 = P12*s2;
            float M20 = P20*s0, M21 = P21*s1, M22 = P22*s2;
            float S00 = M00*M00 + M01*M01 + M02*M02;
            float S01 = M00*M10 + M01*M11 + M02*M12;
            float S02 = M00*M20 + M01*M21 + M02*M22;
            float S11 = M10*M10 + M11*M11 + M12*M12;
            float S12 = M10*M20 + M11*M21 + M12*M22;
            float S22 = M20*M20 + M21*M21 + M22*M22;
            float T00 = C00*S00 + C01*S01 + C02*S02;
            float T01 = C00*S01 + C01*S11 + C02*S12;
            float T02 = C00*S02 + C01*S12 + C02*S22;
            float T10 = C10*S00 + C11*S01 + C12*S02;
            float T11 = C10*S01 + C11*S11 + C12*S12;
            float T12 = C10*S02 + C11*S12 + C12*S22;
            float T20 = C20*S00 + C21*S01 + C22*S02;
            float T21 = C20*S01 + C21*S11 + C22*S12;
            float T22 = C20*S02 + C21*S12 + C22*S22;
            float G00 = T00*C00 + T01*C01 + T02*C02;
            float G01 = T00*C10 + T01*C11 + T02*C12;
            float G02 = T00*C20 + T01*C21 + T02*C22;
            float G11 = T10*C10 + T11*C11 + T12*C12;
            float G12 = T10*C20 + T11*C21 + T12*C22;
            float G22 = T20*C20 + T21*C21 + T22*C22;
            float j00 = fx * inv_z;
            float j02 = -fx * xc * inv_z * inv_z;
            float j11 = fy * inv_z;
            float j12 = -fy * yc * inv_z * inv_z;
            float a0 = j00*G00 + j02*G02;
            float a1 = j00*G01 + j02*G12;
            float a2 = j00*G02 + j02*G22;
            float b1 = j11*G11 + j12*G12;
            float b2 = j11*G12 + j12*G22;
            float cov00 = a0*j00 + a2*j02;
            float cov01 = a1*j11 + a2*j12;
            float cov11 = b1*j11 + b2*j12;

            float A = cov00 + 0.3f;
            float B = cov01;
            float Cc = cov11 + 0.3f;
            float det = fmaxf(A*Cc - B*B, 1e-9f);
            float conic_a = Cc / det;
            float conic_b = -B / det;
            float conic_c = A / det;
            float mid = 0.5f * (A + Cc);
            float lam = mid + sqrtf(fmaxf(mid*mid - det, 1e-9f));
            float radii = ceilf(3.0f * sqrtf(lam));

            float alpha = 1.0f / (1.0f + expf(-fv[7]));

            float dnx = px - tx, dny = py - ty, dnz = pz - tz;
            float dn = sqrtf(dnx*dnx + dny*dny + dnz*dnz);
            float dx = dnx/dn, dy = dny/dn, dz = dnz/dn;
            float xx = dx*dx, yy = dy*dy, zz = dz*dz;
            float xy = dx*dy, yz = dy*dz, xz = dx*dz;
            float basis[16];
            basis[0] = 0.28209479177387814f;
            basis[1] = -0.4886025119029199f * dy;
            basis[2] = 0.4886025119029199f * dz;
            basis[3] = -0.4886025119029199f * dx;
            basis[4] = 1.0925484305920792f * xy;
            basis[5] = -1.0925484305920792f * yz;
            basis[6] = 0.31539156525252005f * (2.f*zz - xx - yy);
            basis[7] = -1.0925484305920792f * xz;
            basis[8] = 0.5462742152960396f * (xx - yy);
            basis[9] = -0.5900435899266435f * dy * (3.f*xx - yy);
            basis[10] = 2.890611442640554f * xy * dz;
            basis[11] = -0.4570457994644658f * dy * (4.f*zz - xx - yy);
            basis[12] = 0.3731763325901154f * dz * (2.f*zz - 3.f*xx - 3.f*yy);
            basis[13] = -0.4570457994644658f * dx * (4.f*zz - xx - yy);
            basis[14] = 1.445305721320277f * dz * (xx - yy);
            basis[15] = -0.5900435899266435f * dx * (xx - 3.f*yy);
            int band = sh_band[0];
            int kc = (band + 1) * (band + 1);
            float c0 = 0.f, c1 = 0.f, c2 = 0.f;
#pragma unroll
            for (int j = 0; j < 16; j++) {
                if (j < kc) {
                    c0 += basis[j] * fv[8 + 0*16 + j];
                    c1 += basis[j] * fv[8 + 1*16 + j];
                    c2 += basis[j] * fv[8 + 2*16 + j];
                }
            }
            c0 = fmaxf(c0 + 0.5f, 0.0f);
            c1 = fmaxf(c1 + 0.5f, 0.0f);
            c2 = fmaxf(c2 + 0.5f, 0.0f);

            float tiles_x = (float)(W / TILE_SZ);
            float tiles_y = (float)(H / TILE_SZ);
            float t0x = fminf(fmaxf(floorf((u - radii) / TILE_SZ), 0.0f), tiles_x - 1.0f);
            float t1x = fminf(fmaxf(floorf((u + radii) / TILE_SZ), 0.0f), tiles_x - 1.0f);
            float t0y = fminf(fmaxf(floorf((v - radii) / TILE_SZ), 0.0f), tiles_y - 1.0f);
            float t1y = fminf(fmaxf(floorf((v + radii) / TILE_SZ), 0.0f), tiles_y - 1.0f);

            unsigned pb;
            float rmax2;
            if (valid) {
                pb = (unsigned)(int)t0x | ((unsigned)(int)t1x << 8)
                   | ((unsigned)(int)t0y << 16) | ((unsigned)(int)t1y << 24);
                rmax2 = 2.0f * lam * logf(255.0f * alpha);
                if (!(rmax2 >= 0.0f)) rmax2 = -1.0f;
                else rmax2 = rmax2 * 1.0005f + 1e-3f;
            } else {
                pb = 0x00FF00FFu;
                rmax2 = -1.0f;
                alpha = 0.0f;
            }

            float4* dst = (float4*)(sorted_recs + (size_t)rank * 16);
            dst[0] = make_float4(u, v, conic_a, conic_b);
            dst[1] = make_float4(conic_c, alpha, zc, c0);
            dst[2] = make_float4(c1, c2, 0.f, 0.f);
            dst[3] = make_float4(u, v, rmax2, __uint_as_float(pb));
        }
    }
}

// R12's measured-best raster, verbatim: one block (4 waves) per 16x16 tile,
// ZERO barriers, per-quadrant cull (box + circle) into wave-private u16
// lists, wave-private double-buffered LDS staging (load-early/ds_write-late).
#define LIST_CAP 2048

#define COMPOSITE(P0,P1,P2) do { \
    float du = pxf - P0.x; \
    float dv = pyf - P0.y; \
    float power = -0.5f * (P0.z*du*du + P1.x*dv*dv) - P0.w*du*dv; \
    float e = __expf(power); \
    float ai = fminf(fminf(P1.y * e, P1.y), 0.99f); \
    bool eff = (ai >= ATHR) && (T > TTHR); \
    float w = eff ? T * ai : 0.0f; \
    cr  += w * P1.w; \
    cg  += w * P2.x; \
    cbl += w * P2.y; \
    dep += w * P1.z; \
    acc += w; \
    cnt_px += eff; \
    T = eff ? T * (1.0f - ai) : T; \
} while (0)

__global__ __launch_bounds__(256) void raster_kernel(
        const float* __restrict__ sorted_recs, int N,
        const int* __restrict__ cam_h,
        const int* __restrict__ cam_w,
        float* __restrict__ out)
{
    int W = cam_w[0], H = cam_h[0];
    int tiles_x = W / TILE_SZ;
    int bx = blockIdx.x % tiles_x;
    int by = blockIdx.x / tiles_x;
    int tid = threadIdx.x;
    int lane = tid & 63;
    int wv = tid >> 6;
    int qpx0 = bx * TILE_SZ + (wv & 1) * 8;
    int qpy0 = by * TILE_SZ + (wv >> 1) * 8;
    int px = qpx0 + (lane & 7);
    int py = qpy0 + (lane >> 3);
    float pxf = (float)px + 0.5f;
    float pyf = (float)py + 0.5f;
    float qx0 = (float)qpx0 + 0.5f, qx1 = (float)qpx0 + 7.5f;
    float qy0 = (float)qpy0 + 0.5f, qy1 = (float)qpy0 + 7.5f;

    float T = 1.0f;
    float cr = 0.f, cg = 0.f, cbl = 0.f;
    float dep = 0.f, acc = 0.f;
    int cnt_px = 0;

    __shared__ unsigned short wlist[4][LIST_CAP];  // 16KB wave-private lists
    __shared__ float swave[4][2][64 * 16];         // 32KB wave-private dbuf

    unsigned short* wl = wlist[wv];
    bool wave_done = false;

    for (int seg = 0; seg < N && !wave_done; seg += LIST_CAP) {
        int segN = min(LIST_CAP, N - seg);

        // ---- membership: per-quadrant cull, wave-local compaction ----
        int cnt = 0;
        for (int base = 0; base < segN; base += 512) {   // 8 rounds per batch
            float4 g[8];
#pragma unroll
            for (int r = 0; r < 8; r++) {
                int local = base + r * 64 + lane;
                if (local < segN) {
                    g[r] = *(const float4*)(sorted_recs + (size_t)(seg + local) * 16 + 12);
                } else {
                    g[r].x = 0.f; g[r].y = 0.f; g[r].z = -1.f;
                    g[r].w = __uint_as_float(0x00FF00FFu);
                }
            }
#pragma unroll
            for (int r = 0; r < 8; r++) {
                unsigned ub = __float_as_uint(g[r].w);
                int b0x = (int)(ub & 0xFFu);
                int b1x = (int)((ub >> 8) & 0xFFu);
                int b0y = (int)((ub >> 16) & 0xFFu);
                int b1y = (int)((ub >> 24) & 0xFFu);
                bool inbox = (bx >= b0x) && (bx <= b1x) && (by >= b0y) && (by <= b1y);
                float dxc = g[r].x - fminf(fmaxf(g[r].x, qx0), qx1);
                float dyc = g[r].y - fminf(fmaxf(g[r].y, qy0), qy1);
                float r2 = dxc*dxc + dyc*dyc;
                bool pred = inbox && (r2 <= g[r].z);
                unsigned long long mm = __ballot(pred);
                if (pred) {
                    int below = __popcll(mm & ((1ull << lane) - 1ull));
                    wl[cnt + below] = (unsigned short)(base + r * 64 + lane);
                }
                cnt += __popcll(mm);
            }
        }

        // ---- barrier-free wave-private double-buffered composite ----
        float* st0 = &swave[wv][0][0];
        float* st1 = &swave[wv][1][0];
        int r0 = lane >> 2;
        int part = lane & 3;

        if (cnt > 0) {
            float4 n0, n1, n2, n3;
            if (r0 < cnt)      n0 = ((const float4*)(sorted_recs + (size_t)(seg + (int)wl[r0]) * 16))[part];
            if (16 + r0 < cnt) n1 = ((const float4*)(sorted_recs + (size_t)(seg + (int)wl[16 + r0]) * 16))[part];
            if (32 + r0 < cnt) n2 = ((const float4*)(sorted_recs + (size_t)(seg + (int)wl[32 + r0]) * 16))[part];
            if (48 + r0 < cnt) n3 = ((const float4*)(sorted_recs + (size_t)(seg + (int)wl[48 + r0]) * 16))[part];
            if (r0 < cnt)      *(float4*)(st0 + (lane) * 4)       = n0;
            if (16 + r0 < cnt) *(float4*)(st0 + (64 + lane) * 4)  = n1;
            if (32 + r0 < cnt) *(float4*)(st0 + (128 + lane) * 4) = n2;
            if (48 + r0 < cnt) *(float4*)(st0 + (192 + lane) * 4) = n3;
        }

        bool wdead = false;
        int buf = 0;
        for (int c = 0; c < cnt && !wdead; c += 64) {
            int ecnt = min(64, cnt - c);
            float* cur = buf ? st1 : st0;
            float* oth = buf ? st0 : st1;
            int cn = c + 64;
            int rem = cnt - cn;

            // issue next-chunk global loads early (latency hides under composite)
            float4 n0, n1, n2, n3;
            if (rem > 0) {
                if (r0 < rem)      n0 = ((const float4*)(sorted_recs + (size_t)(seg + (int)wl[cn + r0]) * 16))[part];
                if (16 + r0 < rem) n1 = ((const float4*)(sorted_recs + (size_t)(seg + (int)wl[cn + 16 + r0]) * 16))[part];
                if (32 + r0 < rem) n2 = ((const float4*)(sorted_recs + (size_t)(seg + (int)wl[cn + 32 + r0]) * 16))[part];
                if (48 + r0 < rem) n3 = ((const float4*)(sorted_recs + (size_t)(seg + (int)wl[cn + 48 + r0]) * 16))[part];
            }

            // composite current chunk (broadcast LDS reads, issue-bound)
            for (int j = 0; j < ecnt; j++) {
                const float* p = cur + j * 16;
                float4 p0 = *(const float4*)p;
                float4 p1 = *(const float4*)(p + 4);
                float4 p2 = *(const float4*)(p + 8);
                COMPOSITE(p0, p1, p2);
            }
            wdead = __all(T <= TTHR);

            // write next chunk into the other buffer (same-wave lgkm ordering)
            if (rem > 0) {
                if (r0 < rem)      *(float4*)(oth + (lane) * 4)       = n0;
                if (16 + r0 < rem) *(float4*)(oth + (64 + lane) * 4)  = n1;
                if (32 + r0 < rem) *(float4*)(oth + (128 + lane) * 4) = n2;
                if (48 + r0 < rem) *(float4*)(oth + (192 + lane) * 4) = n3;
            }
            buf ^= 1;
        }
        wave_done = wdead;
    }

    int pix = py * W + px;
    int HW = H * W;
    out[pix*3 + 0] = cr;
    out[pix*3 + 1] = cg;
    out[pix*3 + 2] = cbl;
    out[HW*3 + pix] = dep / fmaxf(acc, 1e-6f);
    out[HW*4 + pix] = (float)cnt_px;
}

extern "C" void kernel_launch(void* const* d_in, const int* in_sizes, int n_in,
                              void* d_out, int out_size, void* d_ws, size_t ws_size,
                              hipStream_t stream) {
    const float* pc    = (const float*)d_in[0];
    const float* feat  = (const float*)d_in[1];
    const int*   inval = (const int*)d_in[3];
    const float* K     = (const float*)d_in[4];
    const float* qc    = (const float*)d_in[5];
    const float* tc    = (const float*)d_in[6];
    const int*   camH  = (const int*)d_in[7];
    const int*   camW  = (const int*)d_in[8];
    const int*   band  = (const int*)d_in[9];
    float* out = (float*)d_out;

    int N = in_sizes[0] / 3;
    int side = (int)(sqrt((double)(out_size / 5)) + 0.5);
    int H = side, W = side;

    float* sorted_recs = (float*)d_ws;

    int pblocks = (N + 31) / 32;
    prep_rank_scatter_kernel<<<pblocks, 256, 0, stream>>>(
        pc, feat, inval, K, qc, tc, camH, camW, band, sorted_recs, N);

    int tiles = (W / TILE_SZ) * (H / TILE_SZ);
    raster_kernel<<<tiles, 256, 0, stream>>>(sorted_recs, N, camH, camW, out);
}

// Round 16
// 31.120 us; speedup vs baseline: 2.3835x; 1.2879x over previous
//
#include <hip/hip_runtime.h>
#include <math.h>

#define TILE_SZ 16
#define NEARP 0.8f
#define FARP 1000.0f
#define ATHR (1.0f/255.0f)
#define TTHR 0.0001f

// Record layout (16 floats, 64B), float4-aligned groups:
//  g0 [0:3]   = u, v, conic_a, conic_b
//  g1 [4:7]   = conic_c, alpha, z, color_r
//  g2 [8:11]  = color_g, color_b, pad, pad
//  g3 [12:15] = u, v, rmax2, packed_bounds(u8 t0x,t1x,t0y,t1y)  <- membership
// Record N (sentinel) = zeros: alpha=0 -> ai=0 -> no-op in both phases.

// ONE kernel = preprocess + stable rank + direct scatter (R15, measured-best).
#define RANK_CHUNK 2048

__global__ __launch_bounds__(256) void prep_rank_scatter_kernel(
        const float* __restrict__ pc,
        const float* __restrict__ feat,
        const int* __restrict__ invalid_mask,
        const float* __restrict__ K,
        const float* __restrict__ qcam,
        const float* __restrict__ tcam,
        const int* __restrict__ cam_h,
        const int* __restrict__ cam_w,
        const int* __restrict__ sh_band,
        float* __restrict__ sorted_recs,
        int N)
{
    __shared__ float sk[RANK_CHUNK];
    __shared__ int pr[8][33];
    int tid = threadIdx.x;
    int iLocal = tid & 31;
    int slice = tid >> 5;
    int i = blockIdx.x * 32 + iLocal;
    bool live = (i < N);

    if (blockIdx.x == 0 && tid == 0) {
        // zero sentinel record at index N
        float4 z = make_float4(0.f, 0.f, 0.f, 0.f);
        float4* s = (float4*)(sorted_recs + (size_t)N * 16);
        s[0] = z; s[1] = z; s[2] = z; s[3] = z;
    }

    float fx = K[0], cx = K[2], fy = K[4], cy = K[5];
    int H = cam_h[0], W = cam_w[0];

    float qx = qcam[0], qy = qcam[1], qz = qcam[2], qw = qcam[3];
    float qn = sqrtf(qx*qx + qy*qy + qz*qz + qw*qw);
    qx /= qn; qy /= qn; qz /= qn; qw /= qn;
    float R00 = 1.f-2.f*(qy*qy+qz*qz), R01 = 2.f*(qx*qy-qw*qz), R02 = 2.f*(qx*qz+qw*qy);
    float R10 = 2.f*(qx*qy+qw*qz), R11 = 1.f-2.f*(qx*qx+qz*qz), R12 = 2.f*(qy*qz-qw*qx);
    float R20 = 2.f*(qx*qz-qw*qy), R21 = 2.f*(qy*qz+qw*qx), R22 = 1.f-2.f*(qx*qx+qy*qy);
    float C00 = R00, C01 = R10, C02 = R20;
    float C10 = R01, C11 = R11, C12 = R21;
    float C20 = R02, C21 = R12, C22 = R22;
    float tx = tcam[0], ty = tcam[1], tz = tcam[2];
    float tcx = -(C00*tx + C01*ty + C02*tz);
    float tcy = -(C10*tx + C11*ty + C12*tz);
    float tcz = -(C20*tx + C21*ty + C22*tz);

    // ---- own key ----
    float ki = 0.0f;
    if (live) {
        float px = pc[i*3+0], py = pc[i*3+1], pz = pc[i*3+2];
        float xc = C00*px + C01*py + C02*pz + tcx;
        float yc = C10*px + C11*py + C12*pz + tcy;
        float zc = C20*px + C21*py + C22*pz + tcz;
        float inv_z = 1.0f / zc;
        float u = fx * xc * inv_z + cx;
        float v = fy * yc * inv_z + cy;
        bool valid = (invalid_mask[i] == 0) && (zc > NEARP) && (zc < FARP)
                  && (u > -4.0f*TILE_SZ) && (u < (float)W + 4.0f*TILE_SZ)
                  && (v > -4.0f*TILE_SZ) && (v < (float)H + 4.0f*TILE_SZ);
        ki = valid ? zc : INFINITY;
    }

    // ---- chunked cooperative key recompute + 8-way sliced scan ----
    int rank_acc = 0;
    for (int cb = 0; cb < N; cb += RANK_CHUNK) {
        int m = min(RANK_CHUNK, N - cb);
        for (int t = tid; t < m; t += 256) {
            int j = cb + t;
            float px = pc[j*3+0], py = pc[j*3+1], pz = pc[j*3+2];
            float xc = C00*px + C01*py + C02*pz + tcx;
            float yc = C10*px + C11*py + C12*pz + tcy;
            float zc = C20*px + C21*py + C22*pz + tcz;
            float inv_z = 1.0f / zc;
            float u = fx * xc * inv_z + cx;
            float v = fy * yc * inv_z + cy;
            bool valid = (invalid_mask[j] == 0) && (zc > NEARP) && (zc < FARP)
                      && (u > -4.0f*TILE_SZ) && (u < (float)W + 4.0f*TILE_SZ)
                      && (v > -4.0f*TILE_SZ) && (v < (float)H + 4.0f*TILE_SZ);
            sk[t] = valid ? zc : INFINITY;
        }
        __syncthreads();
        if (live) {
            int js = slice * (RANK_CHUNK / 8);
            int je = min(js + (RANK_CHUNK / 8), m);
            int j = js;
            for (; j + 4 <= je; j += 4) {
                float4 k4 = *(const float4*)(sk + j);
                int ja = cb + j;
                rank_acc += (k4.x < ki) || (k4.x == ki && (ja    ) < i);
                rank_acc += (k4.y < ki) || (k4.y == ki && (ja + 1) < i);
                rank_acc += (k4.z < ki) || (k4.z == ki && (ja + 2) < i);
                rank_acc += (k4.w < ki) || (k4.w == ki && (ja + 3) < i);
            }
            for (; j < je; j++) {
                float kj = sk[j];
                rank_acc += (kj < ki) || (kj == ki && (cb + j) < i);
            }
        }
        __syncthreads();
    }
    pr[slice][iLocal] = rank_acc;
    __syncthreads();

    // ---- threads 0..31: full preprocess of own point, direct scatter ----
    if (tid < 32) {
        int ip = blockIdx.x * 32 + tid;
        if (ip < N) {
            int rank = 0;
#pragma unroll
            for (int s = 0; s < 8; s++) rank += pr[s][tid];

            float fv[56];
            const float4* f4 = (const float4*)(feat + (size_t)ip * 56);
#pragma unroll
            for (int k = 0; k < 14; k++) {
                float4 t = f4[k];
                fv[4*k+0] = t.x; fv[4*k+1] = t.y; fv[4*k+2] = t.z; fv[4*k+3] = t.w;
            }
            float px = pc[ip*3+0], py = pc[ip*3+1], pz = pc[ip*3+2];
            float xc = C00*px + C01*py + C02*pz + tcx;
            float yc = C10*px + C11*py + C12*pz + tcy;
            float zc = C20*px + C21*py + C22*pz + tcz;
            float inv_z = 1.0f / zc;
            float u = fx * xc * inv_z + cx;
            float v = fy * yc * inv_z + cy;
            bool valid = (invalid_mask[ip] == 0) && (zc > NEARP) && (zc < FARP)
                      && (u > -4.0f*TILE_SZ) && (u < (float)W + 4.0f*TILE_SZ)
                      && (v > -4.0f*TILE_SZ) && (v < (float)H + 4.0f*TILE_SZ);

            float q0 = fv[0], q1 = fv[1], q2 = fv[2], q3 = fv[3];
            float pn = sqrtf(q0*q0 + q1*q1 + q2*q2 + q3*q3);
            q0 /= pn; q1 /= pn; q2 /= pn; q3 /= pn;
            float P00 = 1.f-2.f*(q1*q1+q2*q2), P01 = 2.f*(q0*q1-q3*q2), P02 = 2.f*(q0*q2+q3*q1);
            float P10 = 2.f*(q0*q1+q3*q2), P11 = 1.f-2.f*(q0*q0+q2*q2), P12 = 2.f*(q1*q2-q3*q0);
            float P20 = 2.f*(q0*q2-q3*q1), P21 = 2.f*(q1*q2+q3*q0), P22 = 1.f-2.f*(q0*q0+q1*q1);
            float s0 = expf(fv[4]), s1 = expf(fv[5]), s2 = expf(fv[6]);
            float M00 = P00*s0, M01 = P01*s1, M02 = P02*s2;
            float M10 = P10*s0, M11 = P11*s1, M12 = P12*s2;
            float M20 = P20*s0, M21 = P21*s1, M22 = P22*s2;
            float S00 = M00*M00 + M01*M01 + M02*M02;
            float S01 = M00*M10 + M01*M11 + M02*M12;
            float S02 = M00*M20 + M01*M21 + M02*M22;
            float S11 = M10*M10 + M11*M11 + M12*M12;
            float S12 = M10*M20 + M11*M21 + M12*M22;
            float S22 = M20*M20 + M21*M21 + M22*M22;
            float T00 = C00*S00 + C01*S01 + C02*S02;
            float T01 = C00*S01 + C01*S11 + C02*S12;
            float T02 = C00*S02 + C01*S12 + C02*S22;
            float T10 = C10*S00 + C11*S01 + C12*S02;
            float T11 = C10*S01 + C11*S11 + C12*S12;
            float T12 = C10*S02 + C11*S12 + C12*S22;
            float T20 = C20*S00 + C21*S01 + C22*S02;
            float T21 = C20*S01 + C21*S11 + C22*S12;
            float T22 = C20*S02 + C21*S12 + C22*S22;
            float G00 = T00*C00 + T01*C01 + T02*C02;
            float G01 = T00*C10 + T01*C11 + T02*C12;
            float G02 = T00*C20 + T01*C21 + T02*C22;
            float G11 = T10*C10 + T11*C11 + T12*C12;
            float G12 = T10*C20 + T11*C21 + T12*C22;
            float G22 = T20*C20 + T21*C21 + T22*C22;
            float j00 = fx * inv_z;
            float j02 = -fx * xc * inv_z * inv_z;
            float j11 = fy * inv_z;
            float j12 = -fy * yc * inv_z * inv_z;
            float a0 = j00*G00 + j02*G02;
            float a1 = j00*G01 + j02*G12;
            float a2 = j00*G02 + j02*G22;
            float b1 = j11*G11 + j12*G12;
            float b2 = j11*G12 + j12*G22;
            float cov00 = a0*j00 + a2*j02;
            float cov01 = a1*j11 + a2*j12;
            float cov11 = b1*j11 + b2*j12;

            float A = cov00 + 0.3f;
            float B = cov01;
            float Cc = cov11 + 0.3f;
            float det = fmaxf(A*Cc - B*B, 1e-9f);
            float conic_a = Cc / det;
            float conic_b = -B / det;
            float conic_c = A / det;
            float mid = 0.5f * (A + Cc);
            float lam = mid + sqrtf(fmaxf(mid*mid - det, 1e-9f));
            float radii = ceilf(3.0f * sqrtf(lam));

            float alpha = 1.0f / (1.0f + expf(-fv[7]));

            float dnx = px - tx, dny = py - ty, dnz = pz - tz;
            float dn = sqrtf(dnx*dnx + dny*dny + dnz*dnz);
            float dx = dnx/dn, dy = dny/dn, dz = dnz/dn;
            float xx = dx*dx, yy = dy*dy, zz = dz*dz;
            float xy = dx*dy, yz = dy*dz, xz = dx*dz;
            float basis[16];
            basis[0] = 0.28209479177387814f;
            basis[1] = -0.4886025119029199f * dy;
            basis[2] = 0.4886025119029199f * dz;
            basis[3] = -0.4886025119029199f * dx;
            basis[4] = 1.0925484305920792f * xy;
            basis[5] = -1.0925484305920792f * yz;
            basis[6] = 0.31539156525252005f * (2.f*zz - xx - yy);
            basis[7] = -1.0925484305920792f * xz;
            basis[8] = 0.5462742152960396f * (xx - yy);
            basis[9] = -0.5900435899266435f * dy * (3.f*xx - yy);
            basis[10] = 2.890611442640554f * xy * dz;
            basis[11] = -0.4570457994644658f * dy * (4.f*zz - xx - yy);
            basis[12] = 0.3731763325901154f * dz * (2.f*zz - 3.f*xx - 3.f*yy);
            basis[13] = -0.4570457994644658f * dx * (4.f*zz - xx - yy);
            basis[14] = 1.445305721320277f * dz * (xx - yy);
            basis[15] = -0.5900435899266435f * dx * (xx - 3.f*yy);
            int band = sh_band[0];
            int kc = (band + 1) * (band + 1);
            float c0 = 0.f, c1 = 0.f, c2 = 0.f;
#pragma unroll
            for (int j = 0; j < 16; j++) {
                if (j < kc) {
                    c0 += basis[j] * fv[8 + 0*16 + j];
                    c1 += basis[j] * fv[8 + 1*16 + j];
                    c2 += basis[j] * fv[8 + 2*16 + j];
                }
            }
            c0 = fmaxf(c0 + 0.5f, 0.0f);
            c1 = fmaxf(c1 + 0.5f, 0.0f);
            c2 = fmaxf(c2 + 0.5f, 0.0f);

            float tiles_x = (float)(W / TILE_SZ);
            float tiles_y = (float)(H / TILE_SZ);
            float t0x = fminf(fmaxf(floorf((u - radii) / TILE_SZ), 0.0f), tiles_x - 1.0f);
            float t1x = fminf(fmaxf(floorf((u + radii) / TILE_SZ), 0.0f), tiles_x - 1.0f);
            float t0y = fminf(fmaxf(floorf((v - radii) / TILE_SZ), 0.0f), tiles_y - 1.0f);
            float t1y = fminf(fmaxf(floorf((v + radii) / TILE_SZ), 0.0f), tiles_y - 1.0f);

            unsigned pb;
            float rmax2;
            if (valid) {
                pb = (unsigned)(int)t0x | ((unsigned)(int)t1x << 8)
                   | ((unsigned)(int)t0y << 16) | ((unsigned)(int)t1y << 24);
                rmax2 = 2.0f * lam * logf(255.0f * alpha);
                if (!(rmax2 >= 0.0f)) rmax2 = -1.0f;
                else rmax2 = rmax2 * 1.0005f + 1e-3f;
            } else {
                pb = 0x00FF00FFu;
                rmax2 = -1.0f;
                alpha = 0.0f;
            }

            float4* dst = (float4*)(sorted_recs + (size_t)rank * 16);
            dst[0] = make_float4(u, v, conic_a, conic_b);
            dst[1] = make_float4(conic_c, alpha, zc, c0);
            dst[2] = make_float4(c1, c2, 0.f, 0.f);
            dst[3] = make_float4(u, v, rmax2, __uint_as_float(pb));
        }
    }
}

// Depth-segmented raster: one block per 8x8 QUADRANT (grid = tiles*4, all
// 256 CUs). 4 waves = 4 depth segments of the sorted list; all waves handle
// the SAME 64 pixels. Phase 1: ungated T-product per segment (exact
// substitute for the gated prefix w.r.t. all outputs). Phase 2: R12's
// composite starting from the prefix T_in. Final: sum segment partials.
#define SEG_CAP 2048

#define PH1(P0,P1) do { \
    float du = pxf - P0.x; \
    float dv = pyf - P0.y; \
    float power = -0.5f * (P0.z*du*du + P1.x*dv*dv) - P0.w*du*dv; \
    float e = __expf(power); \
    float ai = fminf(fminf(P1.y * e, P1.y), 0.99f); \
    Tp = (ai >= ATHR) ? Tp * (1.0f - ai) : Tp; \
} while (0)

#define LDG2(D0,D1, WIDX) do { \
    int _ix = ((unsigned)(WIDX) == 0xFFFFu) ? N : (int)(WIDX); \
    const float4* _p = (const float4*)(sorted_recs + (size_t)_ix * 16); \
    D0 = _p[0]; D1 = _p[1]; } while (0)

#define COMPOSITE(P0,P1,P2) do { \
    float du = pxf - P0.x; \
    float dv = pyf - P0.y; \
    float power = -0.5f * (P0.z*du*du + P1.x*dv*dv) - P0.w*du*dv; \
    float e = __expf(power); \
    float ai = fminf(fminf(P1.y * e, P1.y), 0.99f); \
    bool eff = (ai >= ATHR) && (T > TTHR); \
    float w = eff ? T * ai : 0.0f; \
    cr  += w * P1.w; \
    cg  += w * P2.x; \
    cbl += w * P2.y; \
    dep += w * P1.z; \
    acc += w; \
    cnt_px += eff; \
    T = eff ? T * (1.0f - ai) : T; \
} while (0)

__global__ __launch_bounds__(256) void raster_kernel(
        const float* __restrict__ sorted_recs, int N,
        const int* __restrict__ cam_h,
        const int* __restrict__ cam_w,
        float* __restrict__ out)
{
    int W = cam_w[0], H = cam_h[0];
    int tiles_x = W / TILE_SZ;
    int sub = blockIdx.x & 3;
    int tile = blockIdx.x >> 2;
    int bx = tile % tiles_x;
    int by = tile / tiles_x;
    int tid = threadIdx.x;
    int lane = tid & 63;
    int wv = tid >> 6;                       // depth-segment index
    int qpx0 = bx * TILE_SZ + (sub & 1) * 8;
    int qpy0 = by * TILE_SZ + (sub >> 1) * 8;
    int px = qpx0 + (lane & 7);
    int py = qpy0 + (lane >> 3);
    float pxf = (float)px + 0.5f;
    float pyf = (float)py + 0.5f;
    float qx0 = (float)qpx0 + 0.5f, qx1 = (float)qpx0 + 7.5f;
    float qy0 = (float)qpy0 + 0.5f, qy1 = (float)qpy0 + 7.5f;

    __shared__ unsigned short wlist[4][SEG_CAP + 8];  // ~16.4KB
    __shared__ float swave[4][2][64 * 16];            // 32KB
    __shared__ float TP[4][64];                       // 1KB
    __shared__ float part[4][6][64];                  // 6KB

    unsigned short* wl = wlist[wv];

    int SEGSZ = (N + 3) >> 2;
    int segStart = wv * SEGSZ;
    int segEnd = min(N, segStart + SEGSZ);

    // ---- membership over own segment ----
    int cnt = 0;
    for (int base = segStart; base < segEnd; base += 512) {
        float4 g[8];
#pragma unroll
        for (int r = 0; r < 8; r++) {
            int idx = base + r * 64 + lane;
            if (idx < segEnd) {
                g[r] = *(const float4*)(sorted_recs + (size_t)idx * 16 + 12);
            } else {
                g[r].x = 0.f; g[r].y = 0.f; g[r].z = -1.f;
                g[r].w = __uint_as_float(0x00FF00FFu);
            }
        }
#pragma unroll
        for (int r = 0; r < 8; r++) {
            unsigned ub = __float_as_uint(g[r].w);
            int b0x = (int)(ub & 0xFFu);
            int b1x = (int)((ub >> 8) & 0xFFu);
            int b0y = (int)((ub >> 16) & 0xFFu);
            int b1y = (int)((ub >> 24) & 0xFFu);
            bool inbox = (bx >= b0x) && (bx <= b1x) && (by >= b0y) && (by <= b1y);
            float dxc = g[r].x - fminf(fmaxf(g[r].x, qx0), qx1);
            float dyc = g[r].y - fminf(fmaxf(g[r].y, qy0), qy1);
            float r2 = dxc*dxc + dyc*dyc;
            bool pred = inbox && (r2 <= g[r].z);
            unsigned long long mm = __ballot(pred);
            if (pred) {
                int below = __popcll(mm & ((1ull << lane) - 1ull));
                wl[cnt + below] = (unsigned short)(base + r * 64 + lane);
            }
            cnt += __popcll(mm);
        }
    }

    // ---- phase 1: ungated T-product of own segment (skip last segment) ----
    float Tp = 1.0f;
    if (wv != 3 && cnt > 0) {
        int cntp = (cnt + 7) & ~7;
        if (lane < (cntp - cnt)) wl[cnt + lane] = (unsigned short)0xFFFFu;
        float4 Aa0,Aa1, Ab0,Ab1, Ac0,Ac1, Ad0,Ad1;
        float4 Ba0,Ba1, Bb0,Bb1, Bc0,Bc1, Bd0,Bd1;
        {
            ushort4 ix = *(const ushort4*)(wl);
            LDG2(Aa0,Aa1, ix.x); LDG2(Ab0,Ab1, ix.y);
            LDG2(Ac0,Ac1, ix.z); LDG2(Ad0,Ad1, ix.w);
        }
        bool pdead = false;
        for (int g4 = 0; g4 + 4 < cntp && !pdead; g4 += 8) {
            {
                ushort4 jx = *(const ushort4*)(wl + g4 + 4);
                LDG2(Ba0,Ba1, jx.x); LDG2(Bb0,Bb1, jx.y);
                LDG2(Bc0,Bc1, jx.z); LDG2(Bd0,Bd1, jx.w);
            }
            PH1(Aa0,Aa1); PH1(Ab0,Ab1); PH1(Ac0,Ac1); PH1(Ad0,Ad1);
            if (g4 + 8 < cntp) {
                ushort4 kx = *(const ushort4*)(wl + g4 + 8);
                LDG2(Aa0,Aa1, kx.x); LDG2(Ab0,Ab1, kx.y);
                LDG2(Ac0,Ac1, kx.z); LDG2(Ad0,Ad1, kx.w);
            }
            PH1(Ba0,Ba1); PH1(Bb0,Bb1); PH1(Bc0,Bc1); PH1(Bd0,Bd1);
            pdead = __all(Tp <= TTHR);   // exact: later T_in <= Tp <= TTHR
        }
    }
    TP[wv][lane] = Tp;
    __syncthreads();

    // ---- prefix transmittance (ordered product of earlier segments) ----
    float T = 1.0f;
    for (int s = 0; s < wv; s++) T *= TP[s][lane];

    // ---- phase 2: gated composite from T_in (R12 structure) ----
    float cr = 0.f, cg = 0.f, cbl = 0.f;
    float dep = 0.f, acc = 0.f;
    int cnt_px = 0;

    float* st0 = &swave[wv][0][0];
    float* st1 = &swave[wv][1][0];
    int r0 = lane >> 2;
    int part4 = lane & 3;

    bool wdead = __all(T <= TTHR);
    if (cnt > 0 && !wdead) {
        float4 n0, n1, n2, n3;
        if (r0 < cnt)      n0 = ((const float4*)(sorted_recs + (size_t)wl[r0] * 16))[part4];
        if (16 + r0 < cnt) n1 = ((const float4*)(sorted_recs + (size_t)wl[16 + r0] * 16))[part4];
        if (32 + r0 < cnt) n2 = ((const float4*)(sorted_recs + (size_t)wl[32 + r0] * 16))[part4];
        if (48 + r0 < cnt) n3 = ((const float4*)(sorted_recs + (size_t)wl[48 + r0] * 16))[part4];
        if (r0 < cnt)      *(float4*)(st0 + (lane) * 4)       = n0;
        if (16 + r0 < cnt) *(float4*)(st0 + (64 + lane) * 4)  = n1;
        if (32 + r0 < cnt) *(float4*)(st0 + (128 + lane) * 4) = n2;
        if (48 + r0 < cnt) *(float4*)(st0 + (192 + lane) * 4) = n3;

        int buf = 0;
        for (int c = 0; c < cnt && !wdead; c += 64) {
            int ecnt = min(64, cnt - c);
            float* cur = buf ? st1 : st0;
            float* oth = buf ? st0 : st1;
            int cn = c + 64;
            int rem = cnt - cn;

            float4 m0, m1, m2, m3;
            if (rem > 0) {
                if (r0 < rem)      m0 = ((const float4*)(sorted_recs + (size_t)wl[cn + r0] * 16))[part4];
                if (16 + r0 < rem) m1 = ((const float4*)(sorted_recs + (size_t)wl[cn + 16 + r0] * 16))[part4];
                if (32 + r0 < rem) m2 = ((const float4*)(sorted_recs + (size_t)wl[cn + 32 + r0] * 16))[part4];
                if (48 + r0 < rem) m3 = ((const float4*)(sorted_recs + (size_t)wl[cn + 48 + r0] * 16))[part4];
            }

            for (int j = 0; j < ecnt; j++) {
                const float* p = cur + j * 16;
                float4 p0 = *(const float4*)p;
                float4 p1 = *(const float4*)(p + 4);
                float4 p2 = *(const float4*)(p + 8);
                COMPOSITE(p0, p1, p2);
            }
            wdead = __all(T <= TTHR);

            if (rem > 0) {
                if (r0 < rem)      *(float4*)(oth + (lane) * 4)       = m0;
                if (16 + r0 < rem) *(float4*)(oth + (64 + lane) * 4)  = m1;
                if (32 + r0 < rem) *(float4*)(oth + (128 + lane) * 4) = m2;
                if (48 + r0 < rem) *(float4*)(oth + (192 + lane) * 4) = m3;
            }
            buf ^= 1;
        }
    }

    part[wv][0][lane] = cr;
    part[wv][1][lane] = cg;
    part[wv][2][lane] = cbl;
    part[wv][3][lane] = dep;
    part[wv][4][lane] = acc;
    part[wv][5][lane] = (float)cnt_px;
    __syncthreads();

    // ---- merge segments (ascending) + write ----
    if (wv == 0) {
        float o0 = 0.f, o1 = 0.f, o2 = 0.f, o3 = 0.f, o4 = 0.f, o5 = 0.f;
#pragma unroll
        for (int s = 0; s < 4; s++) {
            o0 += part[s][0][lane];
            o1 += part[s][1][lane];
            o2 += part[s][2][lane];
            o3 += part[s][3][lane];
            o4 += part[s][4][lane];
            o5 += part[s][5][lane];
        }
        int pix = py * W + px;
        int HW = H * W;
        out[pix*3 + 0] = o0;
        out[pix*3 + 1] = o1;
        out[pix*3 + 2] = o2;
        out[HW*3 + pix] = o3 / fmaxf(o4, 1e-6f);
        out[HW*4 + pix] = o5;
    }
}

extern "C" void kernel_launch(void* const* d_in, const int* in_sizes, int n_in,
                              void* d_out, int out_size, void* d_ws, size_t ws_size,
                              hipStream_t stream) {
    const float* pc    = (const float*)d_in[0];
    const float* feat  = (const float*)d_in[1];
    const int*   inval = (const int*)d_in[3];
    const float* K     = (const float*)d_in[4];
    const float* qc    = (const float*)d_in[5];
    const float* tc    = (const float*)d_in[6];
    const int*   camH  = (const int*)d_in[7];
    const int*   camW  = (const int*)d_in[8];
    const int*   band  = (const int*)d_in[9];
    float* out = (float*)d_out;

    int N = in_sizes[0] / 3;
    int side = (int)(sqrt((double)(out_size / 5)) + 0.5);
    int H = side, W = side;

    float* sorted_recs = (float*)d_ws;   // (N+1) records incl. sentinel

    int pblocks = (N + 31) / 32;
    prep_rank_scatter_kernel<<<pblocks, 256, 0, stream>>>(
        pc, feat, inval, K, qc, tc, camH, camW, band, sorted_recs, N);

    int tiles = (W / TILE_SZ) * (H / TILE_SZ);
    raster_kernel<<<tiles * 4, 256, 0, stream>>>(sorted_recs, N, camH, camW, out);
}

// Round 17
// 29.251 us; speedup vs baseline: 2.5358x; 1.0639x over previous
//
#include <hip/hip_runtime.h>
#include <math.h>

#define TILE_SZ 16
#define NEARP 0.8f
#define FARP 1000.0f
#define ATHR (1.0f/255.0f)
#define TTHR 0.0001f

// Record layout (16 floats, 64B), float4-aligned groups:
//  g0 [0:3]   = u, v, conic_a, conic_b
//  g1 [4:7]   = conic_c, alpha, z, color_r
//  g2 [8:11]  = color_g, color_b, pad, pad
//  g3 [12:15] = u, v, rmax2, packed_bounds(u8 t0x,t1x,t0y,t1y)  <- membership
// Record N (sentinel) = zeros: alpha=0 -> ai=0 -> no-op in both phases.

// ONE kernel = preprocess + stable rank + direct scatter (R15, measured-best).
#define RANK_CHUNK 2048

__global__ __launch_bounds__(256) void prep_rank_scatter_kernel(
        const float* __restrict__ pc,
        const float* __restrict__ feat,
        const int* __restrict__ invalid_mask,
        const float* __restrict__ K,
        const float* __restrict__ qcam,
        const float* __restrict__ tcam,
        const int* __restrict__ cam_h,
        const int* __restrict__ cam_w,
        const int* __restrict__ sh_band,
        float* __restrict__ sorted_recs,
        int N)
{
    __shared__ float sk[RANK_CHUNK];
    __shared__ int pr[8][33];
    int tid = threadIdx.x;
    int iLocal = tid & 31;
    int slice = tid >> 5;
    int i = blockIdx.x * 32 + iLocal;
    bool live = (i < N);

    if (blockIdx.x == 0 && tid == 0) {
        float4 z = make_float4(0.f, 0.f, 0.f, 0.f);
        float4* s = (float4*)(sorted_recs + (size_t)N * 16);
        s[0] = z; s[1] = z; s[2] = z; s[3] = z;
    }

    float fx = K[0], cx = K[2], fy = K[4], cy = K[5];
    int H = cam_h[0], W = cam_w[0];

    float qx = qcam[0], qy = qcam[1], qz = qcam[2], qw = qcam[3];
    float qn = sqrtf(qx*qx + qy*qy + qz*qz + qw*qw);
    qx /= qn; qy /= qn; qz /= qn; qw /= qn;
    float R00 = 1.f-2.f*(qy*qy+qz*qz), R01 = 2.f*(qx*qy-qw*qz), R02 = 2.f*(qx*qz+qw*qy);
    float R10 = 2.f*(qx*qy+qw*qz), R11 = 1.f-2.f*(qx*qx+qz*qz), R12 = 2.f*(qy*qz-qw*qx);
    float R20 = 2.f*(qx*qz-qw*qy), R21 = 2.f*(qy*qz+qw*qx), R22 = 1.f-2.f*(qx*qx+qy*qy);
    float C00 = R00, C01 = R10, C02 = R20;
    float C10 = R01, C11 = R11, C12 = R21;
    float C20 = R02, C21 = R12, C22 = R22;
    float tx = tcam[0], ty = tcam[1], tz = tcam[2];
    float tcx = -(C00*tx + C01*ty + C02*tz);
    float tcy = -(C10*tx + C11*ty + C12*tz);
    float tcz = -(C20*tx + C21*ty + C22*tz);

    // ---- own key ----
    float ki = 0.0f;
    if (live) {
        float px = pc[i*3+0], py = pc[i*3+1], pz = pc[i*3+2];
        float xc = C00*px + C01*py + C02*pz + tcx;
        float yc = C10*px + C11*py + C12*pz + tcy;
        float zc = C20*px + C21*py + C22*pz + tcz;
        float inv_z = 1.0f / zc;
        float u = fx * xc * inv_z + cx;
        float v = fy * yc * inv_z + cy;
        bool valid = (invalid_mask[i] == 0) && (zc > NEARP) && (zc < FARP)
                  && (u > -4.0f*TILE_SZ) && (u < (float)W + 4.0f*TILE_SZ)
                  && (v > -4.0f*TILE_SZ) && (v < (float)H + 4.0f*TILE_SZ);
        ki = valid ? zc : INFINITY;
    }

    // ---- chunked cooperative key recompute + 8-way sliced scan ----
    int rank_acc = 0;
    for (int cb = 0; cb < N; cb += RANK_CHUNK) {
        int m = min(RANK_CHUNK, N - cb);
        for (int t = tid; t < m; t += 256) {
            int j = cb + t;
            float px = pc[j*3+0], py = pc[j*3+1], pz = pc[j*3+2];
            float xc = C00*px + C01*py + C02*pz + tcx;
            float yc = C10*px + C11*py + C12*pz + tcy;
            float zc = C20*px + C21*py + C22*pz + tcz;
            float inv_z = 1.0f / zc;
            float u = fx * xc * inv_z + cx;
            float v = fy * yc * inv_z + cy;
            bool valid = (invalid_mask[j] == 0) && (zc > NEARP) && (zc < FARP)
                      && (u > -4.0f*TILE_SZ) && (u < (float)W + 4.0f*TILE_SZ)
                      && (v > -4.0f*TILE_SZ) && (v < (float)H + 4.0f*TILE_SZ);
            sk[t] = valid ? zc : INFINITY;
        }
        __syncthreads();
        if (live) {
            int js = slice * (RANK_CHUNK / 8);
            int je = min(js + (RANK_CHUNK / 8), m);
            int j = js;
            for (; j + 4 <= je; j += 4) {
                float4 k4 = *(const float4*)(sk + j);
                int ja = cb + j;
                rank_acc += (k4.x < ki) || (k4.x == ki && (ja    ) < i);
                rank_acc += (k4.y < ki) || (k4.y == ki && (ja + 1) < i);
                rank_acc += (k4.z < ki) || (k4.z == ki && (ja + 2) < i);
                rank_acc += (k4.w < ki) || (k4.w == ki && (ja + 3) < i);
            }
            for (; j < je; j++) {
                float kj = sk[j];
                rank_acc += (kj < ki) || (kj == ki && (cb + j) < i);
            }
        }
        __syncthreads();
    }
    pr[slice][iLocal] = rank_acc;
    __syncthreads();

    // ---- threads 0..31: full preprocess of own point, direct scatter ----
    if (tid < 32) {
        int ip = blockIdx.x * 32 + tid;
        if (ip < N) {
            int rank = 0;
#pragma unroll
            for (int s = 0; s < 8; s++) rank += pr[s][tid];

            float fv[56];
            const float4* f4 = (const float4*)(feat + (size_t)ip * 56);
#pragma unroll
            for (int k = 0; k < 14; k++) {
                float4 t = f4[k];
                fv[4*k+0] = t.x; fv[4*k+1] = t.y; fv[4*k+2] = t.z; fv[4*k+3] = t.w;
            }
            float px = pc[ip*3+0], py = pc[ip*3+1], pz = pc[ip*3+2];
            float xc = C00*px + C01*py + C02*pz + tcx;
            float yc = C10*px + C11*py + C12*pz + tcy;
            float zc = C20*px + C21*py + C22*pz + tcz;
            float inv_z = 1.0f / zc;
            float u = fx * xc * inv_z + cx;
            float v = fy * yc * inv_z + cy;
            bool valid = (invalid_mask[ip] == 0) && (zc > NEARP) && (zc < FARP)
                      && (u > -4.0f*TILE_SZ) && (u < (float)W + 4.0f*TILE_SZ)
                      && (v > -4.0f*TILE_SZ) && (v < (float)H + 4.0f*TILE_SZ);

            float q0 = fv[0], q1 = fv[1], q2 = fv[2], q3 = fv[3];
            float pn = sqrtf(q0*q0 + q1*q1 + q2*q2 + q3*q3);
            q0 /= pn; q1 /= pn; q2 /= pn; q3 /= pn;
            float P00 = 1.f-2.f*(q1*q1+q2*q2), P01 = 2.f*(q0*q1-q3*q2), P02 = 2.f*(q0*q2+q3*q1);
            float P10 = 2.f*(q0*q1+q3*q2), P11 = 1.f-2.f*(q0*q0+q2*q2), P12 = 2.f*(q1*q2-q3*q0);
            float P20 = 2.f*(q0*q2-q3*q1), P21 = 2.f*(q1*q2+q3*q0), P22 = 1.f-2.f*(q0*q0+q1*q1);
            float s0 = expf(fv[4]), s1 = expf(fv[5]), s2 = expf(fv[6]);
            float M00 = P00*s0, M01 = P01*s1, M02 = P02*s2;
            float M10 = P10*s0, M11 = P11*s1, M12 = P12*s2;
            float M20 = P20*s0, M21 = P21*s1, M22 = P22*s2;
            float S00 = M00*M00 + M01*M01 + M02*M02;
            float S01 = M00*M10 + M01*M11 + M02*M12;
            float S02 = M00*M20 + M01*M21 + M02*M22;
            float S11 = M10*M10 + M11*M11 + M12*M12;
            float S12 = M10*M20 + M11*M21 + M12*M22;
            float S22 = M20*M20 + M21*M21 + M22*M22;
            float T00 = C00*S00 + C01*S01 + C02*S02;
            float T01 = C00*S01 + C01*S11 + C02*S12;
            float T02 = C00*S02 + C01*S12 + C02*S22;
            float T10 = C10*S00 + C11*S01 + C12*S02;
            float T11 = C10*S01 + C11*S11 + C12*S12;
            float T12 = C10*S02 + C11*S12 + C12*S22;
            float T20 = C20*S00 + C21*S01 + C22*S02;
            float T21 = C20*S01 + C21*S11 + C22*S12;
            float T22 = C20*S02 + C21*S12 + C22*S22;
            float G00 = T00*C00 + T01*C01 + T02*C02;
            float G01 = T00*C10 + T01*C11 + T02*C12;
            float G02 = T00*C20 + T01*C21 + T02*C22;
            float G11 = T10*C10 + T11*C11 + T12*C12;
            float G12 = T10*C20 + T11*C21 + T12*C22;
            float G22 = T20*C20 + T21*C21 + T22*C22;
            float j00 = fx * inv_z;
            float j02 = -fx * xc * inv_z * inv_z;
            float j11 = fy * inv_z;
            float j12 = -fy * yc * inv_z * inv_z;
            float a0 = j00*G00 + j02*G02;
            float a1 = j00*G01 + j02*G12;
            float a2 = j00*G02 + j02*G22;
            float b1 = j11*G11 + j12*G12;
            float b2 = j11*G12 + j12*G22;
            float cov00 = a0*j00 + a2*j02;
            float cov01 = a1*j11 + a2*j12;
            float cov11 = b1*j11 + b2*j12;

            float A = cov00 + 0.3f;
            float B = cov01;
            float Cc = cov11 + 0.3f;
            float det = fmaxf(A*Cc - B*B, 1e-9f);
            float conic_a = Cc / det;
            float conic_b = -B / det;
            float conic_c = A / det;
            float mid = 0.5f * (A + Cc);
            float lam = mid + sqrtf(fmaxf(mid*mid - det, 1e-9f));
            float radii = ceilf(3.0f * sqrtf(lam));

            float alpha = 1.0f / (1.0f + expf(-fv[7]));

            float dnx = px - tx, dny = py - ty, dnz = pz - tz;
            float dn = sqrtf(dnx*dnx + dny*dny + dnz*dnz);
            float dx = dnx/dn, dy = dny/dn, dz = dnz/dn;
            float xx = dx*dx, yy = dy*dy, zz = dz*dz;
            float xy = dx*dy, yz = dy*dz, xz = dx*dz;
            float basis[16];
            basis[0] = 0.28209479177387814f;
            basis[1] = -0.4886025119029199f * dy;
            basis[2] = 0.4886025119029199f * dz;
            basis[3] = -0.4886025119029199f * dx;
            basis[4] = 1.0925484305920792f * xy;
            basis[5] = -1.0925484305920792f * yz;
            basis[6] = 0.31539156525252005f * (2.f*zz - xx - yy);
            basis[7] = -1.0925484305920792f * xz;
            basis[8] = 0.5462742152960396f * (xx - yy);
            basis[9] = -0.5900435899266435f * dy * (3.f*xx - yy);
            basis[10] = 2.890611442640554f * xy * dz;
            basis[11] = -0.4570457994644658f * dy * (4.f*zz - xx - yy);
            basis[12] = 0.3731763325901154f * dz * (2.f*zz - 3.f*xx - 3.f*yy);
            basis[13] = -0.4570457994644658f * dx * (4.f*zz - xx - yy);
            basis[14] = 1.445305721320277f * dz * (xx - yy);
            basis[15] = -0.5900435899266435f * dx * (xx - 3.f*yy);
            int band = sh_band[0];
            int kc = (band + 1) * (band + 1);
            float c0 = 0.f, c1 = 0.f, c2 = 0.f;
#pragma unroll
            for (int j = 0; j < 16; j++) {
                if (j < kc) {
                    c0 += basis[j] * fv[8 + 0*16 + j];
                    c1 += basis[j] * fv[8 + 1*16 + j];
                    c2 += basis[j] * fv[8 + 2*16 + j];
                }
            }
            c0 = fmaxf(c0 + 0.5f, 0.0f);
            c1 = fmaxf(c1 + 0.5f, 0.0f);
            c2 = fmaxf(c2 + 0.5f, 0.0f);

            float tiles_x = (float)(W / TILE_SZ);
            float tiles_y = (float)(H / TILE_SZ);
            float t0x = fminf(fmaxf(floorf((u - radii) / TILE_SZ), 0.0f), tiles_x - 1.0f);
            float t1x = fminf(fmaxf(floorf((u + radii) / TILE_SZ), 0.0f), tiles_x - 1.0f);
            float t0y = fminf(fmaxf(floorf((v - radii) / TILE_SZ), 0.0f), tiles_y - 1.0f);
            float t1y = fminf(fmaxf(floorf((v + radii) / TILE_SZ), 0.0f), tiles_y - 1.0f);

            unsigned pb;
            float rmax2;
            if (valid) {
                pb = (unsigned)(int)t0x | ((unsigned)(int)t1x << 8)
                   | ((unsigned)(int)t0y << 16) | ((unsigned)(int)t1y << 24);
                rmax2 = 2.0f * lam * logf(255.0f * alpha);
                if (!(rmax2 >= 0.0f)) rmax2 = -1.0f;
                else rmax2 = rmax2 * 1.0005f + 1e-3f;
            } else {
                pb = 0x00FF00FFu;
                rmax2 = -1.0f;
                alpha = 0.0f;
            }

            float4* dst = (float4*)(sorted_recs + (size_t)rank * 16);
            dst[0] = make_float4(u, v, conic_a, conic_b);
            dst[1] = make_float4(conic_c, alpha, zc, c0);
            dst[2] = make_float4(c1, c2, 0.f, 0.f);
            dst[3] = make_float4(u, v, rmax2, __uint_as_float(pb));
        }
    }
}

// Depth-segmented raster v2: one block per 8x8 QUADRANT, 512 threads =
// 8 waves = 8 depth segments (R16's verified-exact scheme, doubled).
// Phase 1: ungated T-product per segment (exact substitute). Phase 2:
// gated composite from prefix T_in. Merge ascending.
#define NSEG 8
#define SEG_CAP 520   // supports N <= 8*512 = 4096

#define PH1(P0,P1) do { \
    float du = pxf - P0.x; \
    float dv = pyf - P0.y; \
    float power = -0.5f * (P0.z*du*du + P1.x*dv*dv) - P0.w*du*dv; \
    float e = __expf(power); \
    float ai = fminf(fminf(P1.y * e, P1.y), 0.99f); \
    Tp = (ai >= ATHR) ? Tp * (1.0f - ai) : Tp; \
} while (0)

#define LDG2(D0,D1, WIDX) do { \
    int _ix = ((unsigned)(WIDX) == 0xFFFFu) ? N : (int)(WIDX); \
    const float4* _p = (const float4*)(sorted_recs + (size_t)_ix * 16); \
    D0 = _p[0]; D1 = _p[1]; } while (0)

#define COMPOSITE(P0,P1,P2) do { \
    float du = pxf - P0.x; \
    float dv = pyf - P0.y; \
    float power = -0.5f * (P0.z*du*du + P1.x*dv*dv) - P0.w*du*dv; \
    float e = __expf(power); \
    float ai = fminf(fminf(P1.y * e, P1.y), 0.99f); \
    bool eff = (ai >= ATHR) && (T > TTHR); \
    float w = eff ? T * ai : 0.0f; \
    cr  += w * P1.w; \
    cg  += w * P2.x; \
    cbl += w * P2.y; \
    dep += w * P1.z; \
    acc += w; \
    cnt_px += eff; \
    T = eff ? T * (1.0f - ai) : T; \
} while (0)

__global__ __launch_bounds__(512) void raster_kernel(
        const float* __restrict__ sorted_recs, int N,
        const int* __restrict__ cam_h,
        const int* __restrict__ cam_w,
        float* __restrict__ out)
{
    int W = cam_w[0], H = cam_h[0];
    int tiles_x = W / TILE_SZ;
    int sub = blockIdx.x & 3;
    int tile = blockIdx.x >> 2;
    int bx = tile % tiles_x;
    int by = tile / tiles_x;
    int tid = threadIdx.x;
    int lane = tid & 63;
    int wv = tid >> 6;                       // depth-segment index 0..7
    int qpx0 = bx * TILE_SZ + (sub & 1) * 8;
    int qpy0 = by * TILE_SZ + (sub >> 1) * 8;
    int px = qpx0 + (lane & 7);
    int py = qpy0 + (lane >> 3);
    float pxf = (float)px + 0.5f;
    float pyf = (float)py + 0.5f;
    float qx0 = (float)qpx0 + 0.5f, qx1 = (float)qpx0 + 7.5f;
    float qy0 = (float)qpy0 + 0.5f, qy1 = (float)qpy0 + 7.5f;

    __shared__ unsigned short wlist[NSEG][SEG_CAP];   // ~8.3KB
    __shared__ float swave[NSEG][2][64 * 16];         // 64KB
    __shared__ float TP[NSEG][64];                    // 2KB
    __shared__ float part[NSEG][6][64];               // 12KB

    unsigned short* wl = wlist[wv];

    int SEGSZ = (N + NSEG - 1) / NSEG;
    int segStart = wv * SEGSZ;
    int segEnd = min(N, segStart + SEGSZ);

    // ---- membership over own segment (4 ballot-rounds per 256 batch) ----
    int cnt = 0;
    for (int base = segStart; base < segEnd; base += 256) {
        float4 g[4];
#pragma unroll
        for (int r = 0; r < 4; r++) {
            int idx = base + r * 64 + lane;
            if (idx < segEnd) {
                g[r] = *(const float4*)(sorted_recs + (size_t)idx * 16 + 12);
            } else {
                g[r].x = 0.f; g[r].y = 0.f; g[r].z = -1.f;
                g[r].w = __uint_as_float(0x00FF00FFu);
            }
        }
#pragma unroll
        for (int r = 0; r < 4; r++) {
            unsigned ub = __float_as_uint(g[r].w);
            int b0x = (int)(ub & 0xFFu);
            int b1x = (int)((ub >> 8) & 0xFFu);
            int b0y = (int)((ub >> 16) & 0xFFu);
            int b1y = (int)((ub >> 24) & 0xFFu);
            bool inbox = (bx >= b0x) && (bx <= b1x) && (by >= b0y) && (by <= b1y);
            float dxc = g[r].x - fminf(fmaxf(g[r].x, qx0), qx1);
            float dyc = g[r].y - fminf(fmaxf(g[r].y, qy0), qy1);
            float r2 = dxc*dxc + dyc*dyc;
            bool pred = inbox && (r2 <= g[r].z);
            unsigned long long mm = __ballot(pred);
            if (pred) {
                int below = __popcll(mm & ((1ull << lane) - 1ull));
                wl[cnt + below] = (unsigned short)(base + r * 64 + lane);
            }
            cnt += __popcll(mm);
        }
    }

    // ---- phase 1: ungated T-product of own segment (skip last segment) ----
    float Tp = 1.0f;
    if (wv != NSEG - 1 && cnt > 0) {
        int cntp = (cnt + 7) & ~7;
        if (lane < (cntp - cnt)) wl[cnt + lane] = (unsigned short)0xFFFFu;
        float4 Aa0,Aa1, Ab0,Ab1, Ac0,Ac1, Ad0,Ad1;
        float4 Ba0,Ba1, Bb0,Bb1, Bc0,Bc1, Bd0,Bd1;
        {
            ushort4 ix = *(const ushort4*)(wl);
            LDG2(Aa0,Aa1, ix.x); LDG2(Ab0,Ab1, ix.y);
            LDG2(Ac0,Ac1, ix.z); LDG2(Ad0,Ad1, ix.w);
        }
        bool pdead = false;
        for (int g4 = 0; g4 + 4 < cntp && !pdead; g4 += 8) {
            {
                ushort4 jx = *(const ushort4*)(wl + g4 + 4);
                LDG2(Ba0,Ba1, jx.x); LDG2(Bb0,Bb1, jx.y);
                LDG2(Bc0,Bc1, jx.z); LDG2(Bd0,Bd1, jx.w);
            }
            PH1(Aa0,Aa1); PH1(Ab0,Ab1); PH1(Ac0,Ac1); PH1(Ad0,Ad1);
            if (g4 + 8 < cntp) {
                ushort4 kx = *(const ushort4*)(wl + g4 + 8);
                LDG2(Aa0,Aa1, kx.x); LDG2(Ab0,Ab1, kx.y);
                LDG2(Ac0,Ac1, kx.z); LDG2(Ad0,Ad1, kx.w);
            }
            PH1(Ba0,Ba1); PH1(Bb0,Bb1); PH1(Bc0,Bc1); PH1(Bd0,Bd1);
            pdead = __all(Tp <= TTHR);   // exact: later T_in <= Tp <= TTHR
        }
    }
    TP[wv][lane] = Tp;
    __syncthreads();

    // ---- prefix transmittance (ordered product of earlier segments) ----
    float T = 1.0f;
    for (int s = 0; s < wv; s++) T *= TP[s][lane];

    // ---- phase 2: gated composite from T_in ----
    float cr = 0.f, cg = 0.f, cbl = 0.f;
    float dep = 0.f, acc = 0.f;
    int cnt_px = 0;

    float* st0 = &swave[wv][0][0];
    float* st1 = &swave[wv][1][0];
    int r0 = lane >> 2;
    int part4 = lane & 3;

    bool wdead = __all(T <= TTHR);
    if (cnt > 0 && !wdead) {
        float4 n0, n1, n2, n3;
        if (r0 < cnt)      n0 = ((const float4*)(sorted_recs + (size_t)wl[r0] * 16))[part4];
        if (16 + r0 < cnt) n1 = ((const float4*)(sorted_recs + (size_t)wl[16 + r0] * 16))[part4];
        if (32 + r0 < cnt) n2 = ((const float4*)(sorted_recs + (size_t)wl[32 + r0] * 16))[part4];
        if (48 + r0 < cnt) n3 = ((const float4*)(sorted_recs + (size_t)wl[48 + r0] * 16))[part4];
        if (r0 < cnt)      *(float4*)(st0 + (lane) * 4)       = n0;
        if (16 + r0 < cnt) *(float4*)(st0 + (64 + lane) * 4)  = n1;
        if (32 + r0 < cnt) *(float4*)(st0 + (128 + lane) * 4) = n2;
        if (48 + r0 < cnt) *(float4*)(st0 + (192 + lane) * 4) = n3;

        int buf = 0;
        for (int c = 0; c < cnt && !wdead; c += 64) {
            int ecnt = min(64, cnt - c);
            float* cur = buf ? st1 : st0;
            float* oth = buf ? st0 : st1;
            int cn = c + 64;
            int rem = cnt - cn;

            float4 m0, m1, m2, m3;
            if (rem > 0) {
                if (r0 < rem)      m0 = ((const float4*)(sorted_recs + (size_t)wl[cn + r0] * 16))[part4];
                if (16 + r0 < rem) m1 = ((const float4*)(sorted_recs + (size_t)wl[cn + 16 + r0] * 16))[part4];
                if (32 + r0 < rem) m2 = ((const float4*)(sorted_recs + (size_t)wl[cn + 32 + r0] * 16))[part4];
                if (48 + r0 < rem) m3 = ((const float4*)(sorted_recs + (size_t)wl[cn + 48 + r0] * 16))[part4];
            }

            for (int j = 0; j < ecnt; j++) {
                const float* p = cur + j * 16;
                float4 p0 = *(const float4*)p;
                float4 p1 = *(const float4*)(p + 4);
                float4 p2 = *(const float4*)(p + 8);
                COMPOSITE(p0, p1, p2);
            }
            wdead = __all(T <= TTHR);

            if (rem > 0) {
                if (r0 < rem)      *(float4*)(oth + (lane) * 4)       = m0;
                if (16 + r0 < rem) *(float4*)(oth + (64 + lane) * 4)  = m1;
                if (32 + r0 < rem) *(float4*)(oth + (128 + lane) * 4) = m2;
                if (48 + r0 < rem) *(float4*)(oth + (192 + lane) * 4) = m3;
            }
            buf ^= 1;
        }
    }

    part[wv][0][lane] = cr;
    part[wv][1][lane] = cg;
    part[wv][2][lane] = cbl;
    part[wv][3][lane] = dep;
    part[wv][4][lane] = acc;
    part[wv][5][lane] = (float)cnt_px;
    __syncthreads();

    // ---- merge segments (ascending) + write ----
    if (wv == 0) {
        float o0 = 0.f, o1 = 0.f, o2 = 0.f, o3 = 0.f, o4 = 0.f, o5 = 0.f;
#pragma unroll
        for (int s = 0; s < NSEG; s++) {
            o0 += part[s][0][lane];
            o1 += part[s][1][lane];
            o2 += part[s][2][lane];
            o3 += part[s][3][lane];
            o4 += part[s][4][lane];
            o5 += part[s][5][lane];
        }
        int pix = py * W + px;
        int HW = H * W;
        out[pix*3 + 0] = o0;
        out[pix*3 + 1] = o1;
        out[pix*3 + 2] = o2;
        out[HW*3 + pix] = o3 / fmaxf(o4, 1e-6f);
        out[HW*4 + pix] = o5;
    }
}

extern "C" void kernel_launch(void* const* d_in, const int* in_sizes, int n_in,
                              void* d_out, int out_size, void* d_ws, size_t ws_size,
                              hipStream_t stream) {
    const float* pc    = (const float*)d_in[0];
    const float* feat  = (const float*)d_in[1];
    const int*   inval = (const int*)d_in[3];
    const float* K     = (const float*)d_in[4];
    const float* qc    = (const float*)d_in[5];
    const float* tc    = (const float*)d_in[6];
    const int*   camH  = (const int*)d_in[7];
    const int*   camW  = (const int*)d_in[8];
    const int*   band  = (const int*)d_in[9];
    float* out = (float*)d_out;

    int N = in_sizes[0] / 3;
    int side = (int)(sqrt((double)(out_size / 5)) + 0.5);
    int H = side, W = side;

    float* sorted_recs = (float*)d_ws;   // (N+1) records incl. sentinel

    int pblocks = (N + 31) / 32;
    prep_rank_scatter_kernel<<<pblocks, 256, 0, stream>>>(
        pc, feat, inval, K, qc, tc, camH, camW, band, sorted_recs, N);

    int tiles = (W / TILE_SZ) * (H / TILE_SZ);
    raster_kernel<<<tiles * 4, 512, 0, stream>>>(sorted_recs, N, camH, camW, out);
}